// Round 1
// baseline (1224.450 us; speedup 1.0000x reference)
//
#include <hip/hip_runtime.h>
#include <cmath>

// PairNetLayer on MI355X (gfx950). Round 1: correctness-first bf16-MFMA GEMM
// decomposition. All matmuls go through one 64x64x32 MFMA tile template with
// fused epilogues; irrep einsums are flattened to GEMMs via permuted layouts.
//
// Sizes: N=4096 nodes, E=65536 edges, MUL=128, TOT=1152, NM=384.

typedef unsigned short u16;
typedef __bf16 v8bf __attribute__((ext_vector_type(8)));
typedef float  v4f  __attribute__((ext_vector_type(4)));

#define NN 4096
#define EE 65536

__device__ __forceinline__ float b2f(u16 u) {
    union { float f; unsigned i; } x; x.i = ((unsigned)u) << 16; return x.f;
}
__device__ __forceinline__ u16 f2b(float f) {  // round-to-nearest-even
    union { float f; unsigned i; } x; x.f = f;
    unsigned i = x.i;
    return (u16)((i + 0x7FFFu + ((i >> 16) & 1u)) >> 16);
}

// ---------------------------------------------------------------------------
// GEMM: C[M,N] = epi(alpha * A[M,K] @ B[K,N] + bias), A bf16 (lda), B given
// pre-transposed bf16: Bt[n*K + k]. M%64==0, N%64==0, K%32==0 (all true here).
// EPI: 0 = bf16 out; 1 = silu -> bf16 out; 2 = (*mult) -> bf16 out;
//      3/4/5 = irrep scatter (DIM 1/3/5, OFF 0/128/512): out[f32] = v + npa.
// ---------------------------------------------------------------------------
struct GemmP {
    const u16* A; int lda;
    const u16* Bt;
    int M, K, N;
    float alpha;
    const float* bias;   // or null
    u16* outB;           // EPI 0,1,2
    const u16* mult;     // EPI 2
    const float* add;    // EPI 3,4,5 (node_pair_attr)
    float* outF;         // EPI 3,4,5
};

template <int EPI>
__global__ __launch_bounds__(256)
void gemm_k(GemmP p) {
    __shared__ __attribute__((aligned(16))) u16 Al[64][40];  // pad: 2-way-free banks
    __shared__ __attribute__((aligned(16))) u16 Bl[64][40];

    const int m0 = blockIdx.x * 64;
    const int n0 = blockIdx.y * 64;
    const int t  = threadIdx.x;
    const int lane = t & 63;
    const int wid  = t >> 6;
    const int wm = (wid & 1) * 32;   // wave row offset in tile
    const int wn = (wid >> 1) * 32;  // wave col offset in tile
    const int sm = t >> 2;           // staging row 0..63
    const int sk = (t & 3) * 8;      // staging k chunk 0/8/16/24
    const int fr = lane & 15;
    const int q  = lane >> 4;

    v4f acc[2][2] = {};

    const u16* Ag = p.A  + (size_t)(m0 + sm) * p.lda + sk;
    const u16* Bg = p.Bt + (size_t)(n0 + sm) * p.K   + sk;

    for (int k0 = 0; k0 < p.K; k0 += 32) {
        uint4 av = *(const uint4*)(Ag + k0);
        uint4 bv = *(const uint4*)(Bg + k0);
        __syncthreads();
        *(uint4*)(&Al[sm][sk]) = av;
        *(uint4*)(&Bl[sm][sk]) = bv;
        __syncthreads();
        v8bf a0 = *(const v8bf*)(&Al[wm +      fr][q * 8]);
        v8bf a1 = *(const v8bf*)(&Al[wm + 16 + fr][q * 8]);
        v8bf b0 = *(const v8bf*)(&Bl[wn +      fr][q * 8]);
        v8bf b1 = *(const v8bf*)(&Bl[wn + 16 + fr][q * 8]);
        acc[0][0] = __builtin_amdgcn_mfma_f32_16x16x32_bf16(a0, b0, acc[0][0], 0, 0, 0);
        acc[0][1] = __builtin_amdgcn_mfma_f32_16x16x32_bf16(a0, b1, acc[0][1], 0, 0, 0);
        acc[1][0] = __builtin_amdgcn_mfma_f32_16x16x32_bf16(a1, b0, acc[1][0], 0, 0, 0);
        acc[1][1] = __builtin_amdgcn_mfma_f32_16x16x32_bf16(a1, b1, acc[1][1], 0, 0, 0);
    }

    // C/D layout (m89-verified): col = lane&15, row = (lane>>4)*4 + reg
#pragma unroll
    for (int i = 0; i < 2; i++) {
#pragma unroll
        for (int j = 0; j < 2; j++) {
            const int colg = n0 + wn + j * 16 + fr;
            const float bc = p.bias ? p.bias[colg] : 0.0f;
#pragma unroll
            for (int r = 0; r < 4; r++) {
                const int rowg = m0 + wm + i * 16 + q * 4 + r;
                float v = acc[i][j][r] * p.alpha + bc;
                if constexpr (EPI == 0) {
                    p.outB[(size_t)rowg * p.N + colg] = f2b(v);
                } else if constexpr (EPI == 1) {
                    v = v / (1.0f + __expf(-v));  // silu
                    p.outB[(size_t)rowg * p.N + colg] = f2b(v);
                } else if constexpr (EPI == 2) {
                    v *= b2f(p.mult[(size_t)rowg * p.N + colg]);
                    p.outB[(size_t)rowg * p.N + colg] = f2b(v);
                } else {
                    constexpr int DIM = (EPI == 3) ? 1 : ((EPI == 4) ? 3 : 5);
                    constexpr int OFF = (EPI == 3) ? 0 : ((EPI == 4) ? 128 : 512);
                    const int e  = rowg / DIM;
                    const int ii = rowg - e * DIM;
                    const size_t idx = (size_t)e * 1152 + OFF + colg * DIM + ii;
                    p.outF[idx] = v + p.add[idx];
                }
            }
        }
    }
}

// ---------------------------------------------------------------------------
// Weight convert + transpose: dst[n*K+k] = bf16(src[k*N+n])
// ---------------------------------------------------------------------------
struct CvtP { const float* src[15]; u16* dst[15]; int K[15]; int N[15]; };

__global__ void cvt_k(CvtP p) {
    const int j = blockIdx.y;
    const float* s = p.src[j];
    u16* d = p.dst[j];
    const int K = p.K[j], N = p.N[j], tot = K * N;
    for (int idx = blockIdx.x * blockDim.x + threadIdx.x; idx < tot;
         idx += gridDim.x * blockDim.x) {
        const int n = idx / K, k = idx - n * K;
        d[idx] = f2b(s[(size_t)k * N + n]);
    }
}

// ---------------------------------------------------------------------------
// Node-stage prep: f0n = [x0 | ||x1|| | ||x2||] (bf16, N x 384),
// x1p[(n*3+i)*128+u], x2p[(n*5+i)*128+u] permuted copies of node_attr parts.
// ---------------------------------------------------------------------------
__global__ void node_prep_k(const float* __restrict__ na, u16* __restrict__ x1p,
                            u16* __restrict__ x2p, u16* __restrict__ f0n) {
    const int idx = blockIdx.x * blockDim.x + threadIdx.x;
    if (idx >= NN * 128) return;
    const int n = idx >> 7, u = idx & 127;
    const float* row = na + (size_t)n * 1152;
    f0n[(size_t)n * 384 + u] = f2b(row[u]);
    float s1 = 0.f;
#pragma unroll
    for (int i = 0; i < 3; i++) {
        float v = row[128 + u * 3 + i];
        x1p[((size_t)(n * 3 + i)) * 128 + u] = f2b(v);
        s1 += v * v;
    }
    f0n[(size_t)n * 384 + 128 + u] = f2b(sqrtf(s1));
    float s2 = 0.f;
#pragma unroll
    for (int i = 0; i < 5; i++) {
        float v = row[512 + u * 5 + i];
        x2p[((size_t)(n * 5 + i)) * 128 + u] = f2b(v);
        s2 += v * v;
    }
    f0n[(size_t)n * 384 + 256 + u] = f2b(sqrtf(s2));
}

// Node gate: h1p = x1 * g1, h2p = x2 * g2 (norm_gate output parts 1/2)
__global__ void node_gate_k(const float* __restrict__ na, const u16* __restrict__ gn,
                            u16* __restrict__ h1p, u16* __restrict__ h2p) {
    const int idx = blockIdx.x * blockDim.x + threadIdx.x;
    if (idx >= NN * 128) return;
    const int n = idx >> 7, u = idx & 127;
    const float* row = na + (size_t)n * 1152;
    const float g1 = b2f(gn[(size_t)n * 384 + 128 + u]);
#pragma unroll
    for (int i = 0; i < 3; i++)
        h1p[((size_t)(n * 3 + i)) * 128 + u] = f2b(row[128 + u * 3 + i] * g1);
    const float g2 = b2f(gn[(size_t)n * 384 + 256 + u]);
#pragma unroll
    for (int i = 0; i < 5; i++)
        h2p[((size_t)(n * 5 + i)) * 128 + u] = f2b(row[512 + u * 5 + i] * g2);
}

// ---------------------------------------------------------------------------
// we = ssp(edge_attr @ fcE_W1 / 8) @ fcE_W2 / sqrt(8)   (wave per edge)
// ---------------------------------------------------------------------------
__global__ void we_k(const float* __restrict__ ea, const float* __restrict__ W1,
                     const float* __restrict__ W2, u16* __restrict__ we) {
    const int lane = threadIdx.x & 63;
    const int e = blockIdx.x * 4 + (threadIdx.x >> 6);
    const float a = ea[(size_t)e * 64 + lane];
    float t8[8];
#pragma unroll
    for (int h = 0; h < 8; h++) {
        float s = a * W1[lane * 8 + h];
#pragma unroll
        for (int m = 1; m < 64; m <<= 1) s += __shfl_xor(s, m, 64);
        const float x = s * 0.125f;
        const float sp = (x > 20.f) ? x : log1pf(__expf(x));
        t8[h] = sp - 0.6931471805599453f;  // ssp
    }
    float v0 = 0.f, v1 = 0.f;
#pragma unroll
    for (int h = 0; h < 8; h++) {
        v0 += t8[h] * W2[h * 128 + lane];
        v1 += t8[h] * W2[h * 128 + 64 + lane];
    }
    we[(size_t)e * 128 + lane]      = f2b(v0 * 0.3535533905932738f);
    we[(size_t)e * 128 + 64 + lane] = f2b(v1 * 0.3535533905932738f);
}

// ---------------------------------------------------------------------------
// s0 = [0.5*(p_d0+p_s0) | <p_d1,p_s1>/sqrt3 | <p_d2,p_s2>/sqrt5]  (E x 384)
// ---------------------------------------------------------------------------
__global__ void s0_k(const int* __restrict__ dst, const int* __restrict__ src,
                     const u16* __restrict__ na0_0, const u16* __restrict__ na0_1p,
                     const u16* __restrict__ na0_2p, u16* __restrict__ s0) {
    const int e = blockIdx.x, u = threadIdx.x;
    const int d = dst[e], s = src[e];
    const float v0 = 0.5f * (b2f(na0_0[(size_t)d * 128 + u]) + b2f(na0_0[(size_t)s * 128 + u]));
    float ip1 = 0.f;
#pragma unroll
    for (int i = 0; i < 3; i++)
        ip1 += b2f(na0_1p[((size_t)(d * 3 + i)) * 128 + u]) *
               b2f(na0_1p[((size_t)(s * 3 + i)) * 128 + u]);
    float ip2 = 0.f;
#pragma unroll
    for (int i = 0; i < 5; i++)
        ip2 += b2f(na0_2p[((size_t)(d * 5 + i)) * 128 + u]) *
               b2f(na0_2p[((size_t)(s * 5 + i)) * 128 + u]);
    s0[(size_t)e * 384 + u]       = f2b(v0);
    s0[(size_t)e * 384 + 128 + u] = f2b(ip1 * 0.57735026918962576f);
    s0[(size_t)e * 384 + 256 + u] = f2b(ip2 * 0.44721359549995794f);
}

// ---------------------------------------------------------------------------
// node_pair = (na[src]+na[dst]) * w_full, w_full[e,t] = w[e, t/9].
// Emits f0e (=[np0 | ||np1|| | ||np2||]) and permuted np1p/np2p (pre-gate).
// ---------------------------------------------------------------------------
__global__ void pair_k(const int* __restrict__ dst, const int* __restrict__ src,
                       const u16* __restrict__ na_0, const u16* __restrict__ na_1p,
                       const u16* __restrict__ na_2p, const u16* __restrict__ w,
                       u16* __restrict__ f0e, u16* __restrict__ np1p,
                       u16* __restrict__ np2p) {
    __shared__ float wr[128];
    const int e = blockIdx.x, u = threadIdx.x;
    wr[u] = b2f(w[(size_t)e * 128 + u]);
    __syncthreads();
    const int d = dst[e], s = src[e];
    const float v0 = (b2f(na_0[(size_t)d * 128 + u]) + b2f(na_0[(size_t)s * 128 + u])) * wr[u / 9];
    f0e[(size_t)e * 384 + u] = f2b(v0);
    float n1 = 0.f;
#pragma unroll
    for (int i = 0; i < 3; i++) {
        const int t = 128 + u * 3 + i;
        const float v = (b2f(na_1p[((size_t)(d * 3 + i)) * 128 + u]) +
                         b2f(na_1p[((size_t)(s * 3 + i)) * 128 + u])) * wr[t / 9];
        np1p[((size_t)(e * 3 + i)) * 128 + u] = f2b(v);
        n1 += v * v;
    }
    f0e[(size_t)e * 384 + 128 + u] = f2b(sqrtf(n1));
    float n2 = 0.f;
#pragma unroll
    for (int i = 0; i < 5; i++) {
        const int t = 512 + u * 5 + i;
        const float v = (b2f(na_2p[((size_t)(d * 5 + i)) * 128 + u]) +
                         b2f(na_2p[((size_t)(s * 5 + i)) * 128 + u])) * wr[t / 9];
        np2p[((size_t)(e * 5 + i)) * 128 + u] = f2b(v);
        n2 += v * v;
    }
    f0e[(size_t)e * 384 + 256 + u] = f2b(sqrtf(n2));
}

// Edge gate: np1p *= g1, np2p *= g2 (in place)
__global__ void gate_k(const u16* __restrict__ ge, u16* __restrict__ np1p,
                       u16* __restrict__ np2p) {
    const int idx = blockIdx.x * blockDim.x + threadIdx.x;
    if (idx >= EE * 128) return;
    const int e = idx >> 7, u = idx & 127;
    const float g1 = b2f(ge[(size_t)e * 384 + 128 + u]);
#pragma unroll
    for (int i = 0; i < 3; i++) {
        const size_t pth = ((size_t)(e * 3 + i)) * 128 + u;
        np1p[pth] = f2b(b2f(np1p[pth]) * g1);
    }
    const float g2 = b2f(ge[(size_t)e * 384 + 256 + u]);
#pragma unroll
    for (int i = 0; i < 5; i++) {
        const size_t pth = ((size_t)(e * 5 + i)) * 128 + u;
        np2p[pth] = f2b(b2f(np2p[pth]) * g2);
    }
}

// ---------------------------------------------------------------------------
static inline void launch_gemm(hipStream_t st, int epi, const u16* A, int lda,
                               const u16* Bt, int M, int K, int N, float alpha,
                               const float* bias, u16* outB, const u16* mult,
                               const float* add, float* outF) {
    GemmP p{A, lda, Bt, M, K, N, alpha, bias, outB, mult, add, outF};
    dim3 g(M / 64, N / 64), b(256);
    switch (epi) {
        case 0: gemm_k<0><<<g, b, 0, st>>>(p); break;
        case 1: gemm_k<1><<<g, b, 0, st>>>(p); break;
        case 2: gemm_k<2><<<g, b, 0, st>>>(p); break;
        case 3: gemm_k<3><<<g, b, 0, st>>>(p); break;
        case 4: gemm_k<4><<<g, b, 0, st>>>(p); break;
        case 5: gemm_k<5><<<g, b, 0, st>>>(p); break;
    }
}

extern "C" void kernel_launch(void* const* d_in, const int* in_sizes, int n_in,
                              void* d_out, int out_size, void* d_ws, size_t ws_size,
                              hipStream_t stream) {
    (void)in_sizes; (void)n_in; (void)out_size; (void)ws_size;
    const float* node_attr = (const float*)d_in[0];
    const float* edge_attr = (const float*)d_in[1];
    const int*   dst       = (const int*)d_in[2];
    const int*   src       = (const int*)d_in[3];
    const float* npa       = (const float*)d_in[4];
    const float* W_inner   = (const float*)d_in[5];
    const float* b_inner   = (const float*)d_in[6];
    const float* W_n       = (const float*)d_in[7];
    const float* b_n       = (const float*)d_in[8];
    const float* W_out     = (const float*)d_in[9];
    const float* b_out     = (const float*)d_in[10];
    const float* pre_W1    = (const float*)d_in[11];
    const float* pre_b1    = (const float*)d_in[12];
    const float* pre_W2    = (const float*)d_in[13];
    const float* pre_b2    = (const float*)d_in[14];
    const float* ng_W1     = (const float*)d_in[15];
    const float* ng_b1     = (const float*)d_in[16];
    const float* ng_W2     = (const float*)d_in[17];
    const float* ng_b2     = (const float*)d_in[18];
    const float* fcE_W1    = (const float*)d_in[19];
    const float* fcE_W2    = (const float*)d_in[20];
    const float* fc_W1     = (const float*)d_in[21];
    const float* fc_b1     = (const float*)d_in[22];
    const float* fc_W2     = (const float*)d_in[23];
    const float* fc_b2     = (const float*)d_in[24];
    float* out = (float*)d_out;
    u16* W = (u16*)d_ws;

    // ---- workspace layout (u16 elements); total ~292 MB ----
    u16* wbT_inner = W;                  //  3 x 16384
    u16* wbT_n     = W + 49152;
    u16* wbT_out   = W + 98304;
    u16* wbT_pre1  = W + 147456;         //  147456
    u16* wbT_pre2  = W + 294912;
    u16* wbT_ng1   = W + 442368;
    u16* wbT_ng2   = W + 589824;
    u16* wbT_fc1   = W + 737280;         //  49152
    u16* wbT_fc2   = W + 786432;         //  16384
    u16* R1   = W + 802816;              //  25,165,824 shared region
    u16* x1p  = R1;                      //  node scratch (dead before s0)
    u16* x2p  = R1 + 1572864;
    u16* f0n  = R1 + 4194304;
    u16* t1n  = R1 + 5767168;
    u16* gn   = R1 + 7340032;
    u16* hn1p = R1 + 8912896;
    u16* hn2p = R1 + 10485760;
    u16* s0   = R1;                      //  alias: written after node stage done
    u16* t1e  = R1;                      //  alias: written after s0 consumed
    u16* na0_0  = W + 25968640;
    u16* na0_1p = na0_0 + 524288;
    u16* na0_2p = na0_1p + 1572864;
    u16* na_0   = na0_2p + 2621440;
    u16* na_1p  = na_0 + 524288;
    u16* na_2p  = na_1p + 1572864;
    u16* ws1    = na_2p + 2621440;
    u16* weB    = ws1 + 8388608;
    u16* wB     = weB + 8388608;
    u16* f0e    = wB + 8388608;          //  25,165,824
    u16* ge     = f0e;                   //  alias: f0e dead after t1e GEMM
    u16* np1p   = f0e + 25165824;        //  25,165,824
    u16* np2p   = np1p + 25165824;       //  41,943,040

    const float ISQ = 0.08838834764831845f;  // 1/sqrt(128)

    // 1. convert + transpose all GEMM weights to bf16 Bt[n*K+k]
    CvtP cp;
    const float* srcs[15] = {W_inner, W_inner + 16384, W_inner + 32768,
                             W_n, W_n + 16384, W_n + 32768,
                             W_out, W_out + 16384, W_out + 32768,
                             pre_W1, pre_W2, ng_W1, ng_W2, fc_W1, fc_W2};
    u16* dsts[15] = {wbT_inner, wbT_inner + 16384, wbT_inner + 32768,
                     wbT_n, wbT_n + 16384, wbT_n + 32768,
                     wbT_out, wbT_out + 16384, wbT_out + 32768,
                     wbT_pre1, wbT_pre2, wbT_ng1, wbT_ng2, wbT_fc1, wbT_fc2};
    const int Ks[15] = {128,128,128,128,128,128,128,128,128,384,384,384,384,384,128};
    const int Ns[15] = {128,128,128,128,128,128,128,128,128,384,384,384,384,128,128};
    for (int j = 0; j < 15; j++) { cp.src[j]=srcs[j]; cp.dst[j]=dsts[j]; cp.K[j]=Ks[j]; cp.N[j]=Ns[j]; }
    cvt_k<<<dim3(64, 15), dim3(256), 0, stream>>>(cp);

    // 2. node prep (f0n, x1p, x2p)
    node_prep_k<<<dim3(2048), dim3(256), 0, stream>>>(node_attr, x1p, x2p, f0n);

    // 3-5. na0 = irrep_linear(node_attr, W_inner, b_inner)  [perm layouts]
    launch_gemm(stream, 0, f0n, 384, wbT_inner,          4096, 128, 128, ISQ, b_inner, na0_0, 0, 0, 0);
    launch_gemm(stream, 0, x1p, 128, wbT_inner + 16384, 12288, 128, 128, ISQ, nullptr, na0_1p, 0, 0, 0);
    launch_gemm(stream, 0, x2p, 128, wbT_inner + 32768, 20480, 128, 128, ISQ, nullptr, na0_2p, 0, 0, 0);

    // 6-8. node norm_gate (pre): g = silu(f0n@W1+b1)@W2+b2; gate parts
    launch_gemm(stream, 1, f0n, 384, wbT_pre1, 4096, 384, 384, 1.f, pre_b1, t1n, 0, 0, 0);
    launch_gemm(stream, 0, t1n, 384, wbT_pre2, 4096, 384, 384, 1.f, pre_b2, gn, 0, 0, 0);
    node_gate_k<<<dim3(2048), dim3(256), 0, stream>>>(node_attr, gn, hn1p, hn2p);

    // 9-11. na = irrep_linear(gated, W_n, b_n)   [g0 = gn cols 0..127, lda 384]
    launch_gemm(stream, 0, gn,   384, wbT_n,          4096, 128, 128, ISQ, b_n,     na_0,  0, 0, 0);
    launch_gemm(stream, 0, hn1p, 128, wbT_n + 16384, 12288, 128, 128, ISQ, nullptr, na_1p, 0, 0, 0);
    launch_gemm(stream, 0, hn2p, 128, wbT_n + 32768, 20480, 128, 128, ISQ, nullptr, na_2p, 0, 0, 0);

    // 12. we (edge MLP on edge_attr)
    we_k<<<dim3(EE / 4), dim3(256), 0, stream>>>(edge_attr, fcE_W1, fcE_W2, weB);

    // 13. s0 from na0 gathers
    s0_k<<<dim3(EE), dim3(128), 0, stream>>>(dst, src, na0_0, na0_1p, na0_2p, s0);

    // 14-15. ws = silu(s0@fc_W1+b1)@fc_W2+b2 ; w = ws * we
    launch_gemm(stream, 1, s0,  384, wbT_fc1, EE, 384, 128, 1.f, fc_b1, ws1, 0,   0, 0);
    launch_gemm(stream, 2, ws1, 128, wbT_fc2, EE, 128, 128, 1.f, fc_b2, wB,  weB, 0, 0);

    // 16. node_pair build (gather + w_full scale + norms, permuted layouts)
    pair_k<<<dim3(EE), dim3(128), 0, stream>>>(dst, src, na_0, na_1p, na_2p, wB, f0e, np1p, np2p);

    // 17-19. edge norm_gate: g = silu(f0e@ng_W1+b1)@ng_W2+b2; gate np parts
    launch_gemm(stream, 1, f0e, 384, wbT_ng1, EE, 384, 384, 1.f, ng_b1, t1e, 0, 0, 0);
    launch_gemm(stream, 0, t1e, 384, wbT_ng2, EE, 384, 384, 1.f, ng_b2, ge,  0, 0, 0);
    gate_k<<<dim3(32768), dim3(256), 0, stream>>>(ge, np1p, np2p);

    // 20-22. out = irrep_linear(gated, W_out, b_out) + node_pair_attr
    launch_gemm(stream, 3, ge,   384, wbT_out,          EE,     128, 128, ISQ, b_out,   0, 0, npa, out);
    launch_gemm(stream, 4, np1p, 128, wbT_out + 16384,  EE * 3, 128, 128, ISQ, nullptr, 0, 0, npa, out);
    launch_gemm(stream, 5, np2p, 128, wbT_out + 32768,  EE * 5, 128, 128, ISQ, nullptr, 0, 0, npa, out);
}